// Round 7
// baseline (1251.238 us; speedup 1.0000x reference)
//
#include <hip/hip_runtime.h>
#include <float.h>

#define EMBED   64
#define CODES   4096
#define NROWS   65536      // 512*8192/64
#define NELEM   4194304    // 512*8192
#define TH      1.5e-3f    // score-gap flag threshold (fp16 single-product budget)

typedef __attribute__((ext_vector_type(8)))  _Float16 f16x8;  // 8 fp16 in 4 VGPRs
typedef __attribute__((ext_vector_type(8)))  short bf16x8;    // 8 bf16 (small-ws path)
typedef __attribute__((ext_vector_type(16))) float f32x16;    // MFMA 32x32 accumulator

__device__ inline unsigned short f2bf(float f) {              // RNE float->bf16
    unsigned u = __float_as_uint(f);
    u += 0x7fff + ((u >> 16) & 1);
    return (unsigned short)(u >> 16);
}
__device__ inline float bf2f(unsigned short h) {
    return __uint_as_float(((unsigned)h) << 16);
}

// ws layout (big): [0,16K) cbuf fp32; [16K] double accum; [32K,544K+32K) packed f16 B-frags;
//                  [557056,+1M) ET fp32; [1605632,+1M) part_a float2; [2654208,+512K) part_i
#define WS_PACKED   32768
#define WS_ET       557056
#define WS_PARTA    1605632
#define WS_PARTI    2654208
#define WS_NEED     3178496

// Fused setup: blocks 0..15 cbuf(+accum), 16..143 pack f16 (e*64), 144..399 ET.
__global__ void vq_setup(const float* __restrict__ E, float* __restrict__ cbuf,
                         double* __restrict__ accum, f16x8* __restrict__ packed,
                         float* __restrict__ ET, int full) {
    const int b = blockIdx.x, t = threadIdx.x;
    if (b < 16) {
        // cbuf: emulate np.sum(E*E, axis=0) (C-order: sequential i, mul/add rounded)
        int j = b * 256 + t;
        float v = E[j];
        float s = __fmul_rn(v, v);
        for (int i = 1; i < EMBED; ++i) {
            v = E[(size_t)i * CODES + j];
            s = __fadd_rn(s, __fmul_rn(v, v));
        }
        cbuf[j] = s;
        if (j == 0) *accum = 0.0;           // d_ws poisoned 0xAA before every launch
    } else if (b < 144) {
        if (!full) return;
        // pack E into MFMA B-fragment order, fp16, scaled by 64 (avoid subnormals)
        int id = (b - 16) * 256 + t;        // [0, 32768)
        int lam = id & 63, kk = (id >> 6) & 3, g = id >> 8;
        int n  = g * 32 + (lam & 31);
        int kb = kk * 16 + (lam >> 5) * 8;
        f16x8 v;
#pragma unroll
        for (int j = 0; j < 8; ++j)
            v[j] = (_Float16)(64.0f * E[(size_t)(kb + j) * CODES + n]);
        packed[id] = v;
    } else {
        if (!full) return;
        // ET = E^T (fp32) for the coalesced output gather
        int id = (b - 144) * 256 + t;       // [0, 65536)
        int j = id >> 4, i0 = (id & 15) * 4;
        float4 v;
        v.x = E[(size_t)(i0 + 0) * CODES + j];
        v.y = E[(size_t)(i0 + 1) * CODES + j];
        v.z = E[(size_t)(i0 + 2) * CODES + j];
        v.w = E[(size_t)(i0 + 3) * CODES + j];
        *(float4*)(ET + (size_t)j * EMBED + i0) = v;
    }
}

// Stage 1: per (row-group, code-half): partial top-2 over 2048 codes.
// acc = 256*x.e - 128*c = -128*score ; maximize.
__global__ __launch_bounds__(256, 4)
void vq_partial(const float* __restrict__ X, const float* __restrict__ cbuf,
                const f16x8* __restrict__ packed, float2* __restrict__ part_a,
                int* __restrict__ part_i) {
    __shared__ f16x8 lbuf[2][1024];         // 2 x 16 KB double buffer

    const int t  = threadIdx.x;
    const int l  = t & 63, wv = t >> 6;
    const int m  = l & 31, h  = l >> 5;
    const int rg   = blockIdx.x >> 1;       // row-group
    const int half = blockIdx.x & 1;        // code half
    const int row0 = rg * 128;

    // A fragments: fp16(4*x), persistent
    f16x8 ah[4];
    {
        const float* xrow = X + (size_t)(row0 + wv * 32 + m) * EMBED;
#pragma unroll
        for (int kk = 0; kk < 4; ++kk) {
            int kb = kk * 16 + h * 8;
            float4 v0 = *(const float4*)(xrow + kb);
            float4 v1 = *(const float4*)(xrow + kb + 4);
            float xv[8] = {v0.x, v0.y, v0.z, v0.w, v1.x, v1.y, v1.z, v1.w};
#pragma unroll
            for (int j = 0; j < 8; ++j) ah[kk][j] = (_Float16)(4.0f * xv[j]);
        }
    }

    float M1[16], M2[16];
#pragma unroll
    for (int e = 0; e < 16; ++e) { M1[e] = -FLT_MAX; M2[e] = -FLT_MAX; }

    auto stage = [&](int ch, int buf) {
#pragma unroll
        for (int q = 0; q < 4; ++q) {
            const f16x8* gp = packed + half * 16384 + ch * 1024 + q * 256 + t;
            f16x8* lp = &lbuf[buf][q * 256 + wv * 64];   // wave-uniform base + lane*16
            __builtin_amdgcn_global_load_lds(
                (const __attribute__((address_space(1))) void*)gp,
                (__attribute__((address_space(3))) void*)lp, 16, 0, 0);
        }
    };

    const int ch0 = rg & 15;                // rotate chunk order across blocks
    stage(ch0, 0);
    __syncthreads();

    int b = 0;
#pragma unroll 1
    for (int cc = 0; cc < 16; ++cc) {
        int ch = (ch0 + cc) & 15;
        if (cc + 1 < 16) stage((ch + 1) & 15, b ^ 1);
        const f16x8* lb = lbuf[b];
#pragma unroll
        for (int tl = 0; tl < 4; ++tl) {
            const int g = half * 64 + ch * 4 + tl;       // global tile id, 7 bits
            f16x8 Bf[4];
#pragma unroll
            for (int kk = 0; kk < 4; ++kk) Bf[kk] = lb[tl * 256 + kk * 64 + l];
            float nc = -128.0f * cbuf[g * 32 + m];
            f32x16 acc;
#pragma unroll
            for (int e = 0; e < 16; ++e) acc[e] = nc;
#pragma unroll
            for (int kk = 0; kk < 4; ++kk)
                acc = __builtin_amdgcn_mfma_f32_32x32x16_f16(ah[kk], Bf[kk], acc, 0, 0, 0);
            unsigned gu = (unsigned)g;
#pragma unroll
            for (int e = 0; e < 16; ++e) {
                float ap = __uint_as_float((__float_as_uint(acc[e]) & 0xFFFFFF80u) | gu);
                float m1o = M1[e];
                M1[e] = fmaxf(m1o, ap);
                M2[e] = __builtin_amdgcn_fmed3f(m1o, M2[e], ap);
            }
        }
        __syncthreads();
        b ^= 1;
    }

    // extract idx, cross-lane top-2 merge within each 32-lane half
    int I1[16];
#pragma unroll
    for (int e = 0; e < 16; ++e)
        I1[e] = (int)(((__float_as_uint(M1[e]) & 0x7Fu) << 5) | (unsigned)m);
#pragma unroll
    for (int d = 1; d < 32; d <<= 1) {
#pragma unroll
        for (int e = 0; e < 16; ++e) {
            float oM1 = __shfl_xor(M1[e], d, 64);
            float oM2 = __shfl_xor(M2[e], d, 64);
            int   oI  = __shfl_xor(I1[e], d, 64);
            float lo  = fminf(M1[e], oM1);
            M2[e] = fmaxf(lo, fmaxf(M2[e], oM2));
            bool c = oM1 > M1[e];
            I1[e] = c ? oI : I1[e];
            M1[e] = c ? oM1 : M1[e];
        }
    }
    // C/D row = (reg&3) + 8*(reg>>2) + 4*(lane>>5)
#pragma unroll
    for (int e = 0; e < 16; ++e) {
        int r = (e & 3) + 8 * (e >> 2) + 4 * h;
        if (m == r) {
            int gr = row0 + wv * 32 + r;
            part_a[half * NROWS + gr] = make_float2(M1[e], M2[e]);
            part_i[half * NROWS + gr] = I1[e];
        }
    }
}

// Stage 2: merge halves, exact fallback for near-ties, write idx/loss/quantized.
__global__ __launch_bounds__(256)
void vq_final(const float* __restrict__ X, const float* __restrict__ E,
              const float* __restrict__ cbuf, const float2* __restrict__ part_a,
              const int* __restrict__ part_i, const float* __restrict__ ET,
              double* __restrict__ accum, float* __restrict__ out) {
    __shared__ int   rowidx[128], rowflg[128];
    __shared__ float term[128];
    __shared__ float fredv[256];
    __shared__ int   fredi[256];

    const int t = threadIdx.x;
    const int row0 = blockIdx.x * 128;

    if (t < 128) {
        int gr = row0 + t;
        float2 p0 = part_a[gr], p1 = part_a[NROWS + gr];
        int    j0 = part_i[gr], j1 = part_i[NROWS + gr];
        bool c = p1.x > p0.x;
        float M1 = c ? p1.x : p0.x;
        float M2 = fmaxf(c ? p0.x : p1.x, c ? p1.y : p0.y);
        rowidx[t] = c ? j1 : j0;
        rowflg[t] = ((M1 - M2) < 128.0f * TH) ? 1 : 0;
        float M1c = __uint_as_float(__float_as_uint(M1) & 0xFFFFFF80u);
        const float* xr = X + (size_t)gr * EMBED;
        float sq = 0.f;
#pragma unroll
        for (int i = 0; i < EMBED; ++i) sq = fmaf(xr[i], xr[i], sq);
        term[t] = sq - M1c * (1.0f / 128.0f);   // ||x||^2 + score_min
    }
    __syncthreads();

    // exact fallback: bit-exact fp32 numpy-reference emulation (uniform branch)
#pragma unroll 1
    for (int r = 0; r < 128; ++r) {
        if (rowflg[r] == 0) continue;
        const float* xr = X + (size_t)(row0 + r) * EMBED;
        // A: numpy pairwise sum of x*x (n=64: 8 accumulators + tree combine)
        float racc[8];
#pragma unroll
        for (int jq = 0; jq < 8; ++jq) racc[jq] = __fmul_rn(xr[jq], xr[jq]);
#pragma unroll
        for (int i = 8; i < 64; i += 8)
#pragma unroll
            for (int jq = 0; jq < 8; ++jq)
                racc[jq] = __fadd_rn(racc[jq], __fmul_rn(xr[i + jq], xr[i + jq]));
        float A = __fadd_rn(
            __fadd_rn(__fadd_rn(racc[0], racc[1]), __fadd_rn(racc[2], racc[3])),
            __fadd_rn(__fadd_rn(racc[4], racc[5]), __fadd_rn(racc[6], racc[7])));

        float best = FLT_MAX; int bestj = CODES;
#pragma unroll 1
        for (int jj = 0; jj < 16; ++jj) {
            int j = jj * 256 + t;
            float mm = 0.f;
#pragma unroll
            for (int i = 0; i < 64; ++i)
                mm = fmaf(xr[i], E[(size_t)i * CODES + j], mm);  // sequential FMA (BLAS k-loop)
            float d = __fadd_rn(__fsub_rn(A, __fmul_rn(2.f, mm)), cbuf[j]);
            if (d < best || (d == best && j < bestj)) { best = d; bestj = j; }
        }
        fredv[t] = best; fredi[t] = bestj;
        __syncthreads();
        if (t == 0) {
            float B = fredv[0]; int BI = fredi[0];
            for (int c2 = 1; c2 < 256; ++c2) {
                float dc = fredv[c2]; int jc = fredi[c2];
                if (dc < B || (dc == B && jc < BI)) { B = dc; BI = jc; }
            }
            rowidx[r] = BI;
        }
        __syncthreads();
    }

    // outputs
    if (t < 128) out[(size_t)NELEM + 1 + row0 + t] = (float)rowidx[t];  // idx as float
    if (t == 0) {
        float bs = 0.f;
        for (int r = 0; r < 128; ++r) bs += term[r];
        atomicAdd(accum, (double)bs);
    }
    {
        int r = t >> 1, i0 = (t & 1) * 32;
        int j = rowidx[r];
        float* dst = out + (size_t)(row0 + r) * EMBED + i0;
        const float* src = ET + (size_t)j * EMBED + i0;
#pragma unroll
        for (int g = 0; g < 8; ++g)
            *(float4*)(dst + g * 4) = *(const float4*)(src + g * 4);
    }
}

// Self-contained safety net if ws is too small: bf16 3-split, on-the-fly convert.
__global__ __launch_bounds__(256)
void vq_small(const float* __restrict__ X, const float* __restrict__ E,
              const float* __restrict__ cbuf, double* __restrict__ accum,
              float* __restrict__ out) {
    __shared__ float rowm1[128], rowsq[128];
    __shared__ int   rowidx[128], rowflg[128];
    __shared__ float fredv[256];
    __shared__ int   fredi[256];

    const int t  = threadIdx.x;
    const int l  = t & 63, wv = t >> 6;
    const int m  = l & 31, h  = l >> 5;
    const int row0 = blockIdx.x * 128;

    bf16x8 ah[4], al[4];
    float sqreg;
    {
        const float* xrow = X + (size_t)(row0 + wv * 32 + m) * EMBED;
        float sq = 0.f;
#pragma unroll
        for (int kk = 0; kk < 4; ++kk) {
            int kb = kk * 16 + h * 8;
            float4 v0 = *(const float4*)(xrow + kb);
            float4 v1 = *(const float4*)(xrow + kb + 4);
            float xv[8] = {v0.x, v0.y, v0.z, v0.w, v1.x, v1.y, v1.z, v1.w};
#pragma unroll
            for (int j = 0; j < 8; ++j) {
                sq = fmaf(xv[j], xv[j], sq);
                unsigned short hi = f2bf(xv[j]);
                ah[kk][j] = (short)hi;
                al[kk][j] = (short)f2bf(xv[j] - bf2f(hi));
            }
        }
        sq += __shfl_xor(sq, 32, 64);
        sqreg = sq;
    }

    float M1[16], M2[16];
#pragma unroll
    for (int e = 0; e < 16; ++e) { M1[e] = -FLT_MAX; M2[e] = -FLT_MAX; }

#pragma unroll 1
    for (int g = 0; g < 128; ++g) {
        bf16x8 B[8];
        int n = g * 32 + m;
#pragma unroll
        for (int kk = 0; kk < 4; ++kk) {
            const float* ec = E + (size_t)(kk * 16 + h * 8) * CODES + n;
            bf16x8 vh, vl;
#pragma unroll
            for (int j = 0; j < 8; ++j) {
                float e = ec[(size_t)j * CODES];
                unsigned short hi = f2bf(e);
                vh[j] = (short)hi;
                vl[j] = (short)f2bf(e - bf2f(hi));
            }
            B[kk * 2] = vh; B[kk * 2 + 1] = vl;
        }
        float nc = -0.5f * cbuf[g * 32 + m];
        f32x16 acc;
#pragma unroll
        for (int e = 0; e < 16; ++e) acc[e] = nc;
#pragma unroll
        for (int kk = 0; kk < 4; ++kk) {
            acc = __builtin_amdgcn_mfma_f32_32x32x16_bf16(ah[kk], B[kk * 2],     acc, 0, 0, 0);
            acc = __builtin_amdgcn_mfma_f32_32x32x16_bf16(ah[kk], B[kk * 2 + 1], acc, 0, 0, 0);
            acc = __builtin_amdgcn_mfma_f32_32x32x16_bf16(al[kk], B[kk * 2],     acc, 0, 0, 0);
        }
        unsigned gu = (unsigned)g;
#pragma unroll
        for (int e = 0; e < 16; ++e) {
            float ap = __uint_as_float((__float_as_uint(acc[e]) & 0xFFFFFF80u) | gu);
            float m1o = M1[e];
            M1[e] = fmaxf(m1o, ap);
            M2[e] = __builtin_amdgcn_fmed3f(m1o, M2[e], ap);
        }
    }

    int I1[16];
#pragma unroll
    for (int e = 0; e < 16; ++e)
        I1[e] = (int)(((__float_as_uint(M1[e]) & 0x7Fu) << 5) | (unsigned)m);
#pragma unroll
    for (int d = 1; d < 32; d <<= 1) {
#pragma unroll
        for (int e = 0; e < 16; ++e) {
            float oM1 = __shfl_xor(M1[e], d, 64);
            float oM2 = __shfl_xor(M2[e], d, 64);
            int   oI  = __shfl_xor(I1[e], d, 64);
            float lo  = fminf(M1[e], oM1);
            M2[e] = fmaxf(lo, fmaxf(M2[e], oM2));
            bool c = oM1 > M1[e];
            I1[e] = c ? oI : I1[e];
            M1[e] = c ? oM1 : M1[e];
        }
    }
    if (h == 0) rowsq[wv * 32 + m] = sqreg;
#pragma unroll
    for (int e = 0; e < 16; ++e) {
        int r = (e & 3) + 8 * (e >> 2) + 4 * h;
        if (m == r) {
            rowm1[wv * 32 + r]  = __uint_as_float(__float_as_uint(M1[e]) & 0xFFFFFF80u);
            rowidx[wv * 32 + r] = I1[e];
            rowflg[wv * 32 + r] = (2.f * (M1[e] - M2[e]) < 2e-4f) ? 1 : 0;
        }
    }
    __syncthreads();

#pragma unroll 1
    for (int r = 0; r < 128; ++r) {
        if (rowflg[r] == 0) continue;
        const float* xr = X + (size_t)(row0 + r) * EMBED;
        float racc[8];
#pragma unroll
        for (int jq = 0; jq < 8; ++jq) racc[jq] = __fmul_rn(xr[jq], xr[jq]);
#pragma unroll
        for (int i = 8; i < 64; i += 8)
#pragma unroll
            for (int jq = 0; jq < 8; ++jq)
                racc[jq] = __fadd_rn(racc[jq], __fmul_rn(xr[i + jq], xr[i + jq]));
        float A = __fadd_rn(
            __fadd_rn(__fadd_rn(racc[0], racc[1]), __fadd_rn(racc[2], racc[3])),
            __fadd_rn(__fadd_rn(racc[4], racc[5]), __fadd_rn(racc[6], racc[7])));
        float best = FLT_MAX; int bestj = CODES;
#pragma unroll 1
        for (int jj = 0; jj < 16; ++jj) {
            int j = jj * 256 + t;
            float mm = 0.f;
#pragma unroll
            for (int i = 0; i < 64; ++i)
                mm = fmaf(xr[i], E[(size_t)i * CODES + j], mm);
            float d = __fadd_rn(__fsub_rn(A, __fmul_rn(2.f, mm)), cbuf[j]);
            if (d < best || (d == best && j < bestj)) { best = d; bestj = j; }
        }
        fredv[t] = best; fredi[t] = bestj;
        __syncthreads();
        if (t == 0) {
            float B = fredv[0]; int BI = fredi[0];
            for (int c2 = 1; c2 < 256; ++c2) {
                float dc = fredv[c2]; int jc = fredi[c2];
                if (dc < B || (dc == B && jc < BI)) { B = dc; BI = jc; }
            }
            rowidx[r] = BI;
        }
        __syncthreads();
    }

    if (t < 128) out[(size_t)NELEM + 1 + row0 + t] = (float)rowidx[t];
    if (t == 0) {
        float bs = 0.f;
        for (int r = 0; r < 128; ++r) bs += rowsq[r] - 2.f * rowm1[r];
        atomicAdd(accum, (double)bs);
    }
    {
        int r = t >> 1, i0 = (t & 1) * 32;
        int j = rowidx[r];
        float* dst = out + (size_t)(row0 + r) * EMBED + i0;
#pragma unroll
        for (int g = 0; g < 8; ++g) {
            float4 v;
            v.x = E[(size_t)(i0 + g * 4 + 0) * CODES + j];
            v.y = E[(size_t)(i0 + g * 4 + 1) * CODES + j];
            v.z = E[(size_t)(i0 + g * 4 + 2) * CODES + j];
            v.w = E[(size_t)(i0 + g * 4 + 3) * CODES + j];
            *(float4*)(dst + g * 4) = v;
        }
    }
}

__global__ void vq_finalize(const double* __restrict__ accum, float* __restrict__ out) {
    out[NELEM] = (float)(0.25 * (*accum) / (double)NELEM);
}

extern "C" void kernel_launch(void* const* d_in, const int* in_sizes, int n_in,
                              void* d_out, int out_size, void* d_ws, size_t ws_size,
                              hipStream_t stream) {
    const float* X = (const float*)d_in[0];   // (512, 8192, 1) f32 -> 65536 rows x 64
    const float* E = (const float*)d_in[1];   // (64, 4096) f32 row-major
    float* out = (float*)d_out;
    float*  cbuf   = (float*)d_ws;
    double* accum  = (double*)((char*)d_ws + 16384);
    f16x8*  packed = (f16x8*)((char*)d_ws + WS_PACKED);
    float*  ET     = (float*)((char*)d_ws + WS_ET);
    float2* part_a = (float2*)((char*)d_ws + WS_PARTA);
    int*    part_i = (int*)((char*)d_ws + WS_PARTI);
    const bool big = (ws_size >= WS_NEED);    // constant across calls -> same work every call

    vq_setup<<<big ? 400 : 16, 256, 0, stream>>>(E, cbuf, accum, packed, ET, big ? 1 : 0);
    if (big) {
        vq_partial<<<1024, 256, 0, stream>>>(X, cbuf, packed, part_a, part_i);
        vq_final<<<512, 256, 0, stream>>>(X, E, cbuf, part_a, part_i, ET, accum, out);
    } else {
        vq_small<<<512, 256, 0, stream>>>(X, E, cbuf, accum, out);
    }
    vq_finalize<<<1, 1, 0, stream>>>(accum, out);
}

// Round 8
// 601.341 us; speedup vs baseline: 2.0807x; 2.0807x over previous
//
#include <hip/hip_runtime.h>
#include <float.h>

#define EMBED   64
#define CODES   4096
#define NROWS   65536      // 512*8192/64
#define NELEM   4194304    // 512*8192
#define TH      1.5e-3f    // score-gap flag threshold (fp16 single-product budget)

typedef __attribute__((ext_vector_type(8)))  _Float16 f16x8;  // 8 fp16 in 4 VGPRs
typedef __attribute__((ext_vector_type(8)))  short bf16x8;    // 8 bf16 (small-ws path)
typedef __attribute__((ext_vector_type(16))) float f32x16;    // MFMA 32x32 accumulator

__device__ inline unsigned short f2bf(float f) {              // RNE float->bf16
    unsigned u = __float_as_uint(f);
    u += 0x7fff + ((u >> 16) & 1);
    return (unsigned short)(u >> 16);
}
__device__ inline float bf2f(unsigned short h) {
    return __uint_as_float(((unsigned)h) << 16);
}

// ws layout (big): [0,16K) cbuf fp32; [16K] double accum; [32K,+512K) packed f16 B-frags;
//                  [557056,+1M) ET fp32; [1605632,+1M) part_a float2; [2654208,+512K) part_i
#define WS_PACKED   32768
#define WS_ET       557056
#define WS_PARTA    1605632
#define WS_PARTI    2654208
#define WS_NEED     3178496

// Fused setup: blocks 0..15 cbuf(+accum), 16..143 pack f16 (e*64), 144..399 ET.
__global__ void vq_setup(const float* __restrict__ E, float* __restrict__ cbuf,
                         double* __restrict__ accum, f16x8* __restrict__ packed,
                         float* __restrict__ ET, int full) {
    const int b = blockIdx.x, t = threadIdx.x;
    if (b < 16) {
        // cbuf: emulate np.sum(E*E, axis=0) (C-order: sequential i, mul/add rounded)
        int j = b * 256 + t;
        float v = E[j];
        float s = __fmul_rn(v, v);
        for (int i = 1; i < EMBED; ++i) {
            v = E[(size_t)i * CODES + j];
            s = __fadd_rn(s, __fmul_rn(v, v));
        }
        cbuf[j] = s;
        if (j == 0) *accum = 0.0;           // d_ws poisoned 0xAA before every launch
    } else if (b < 144) {
        if (!full) return;
        // pack E into MFMA B-fragment order, fp16, scaled by 64 (avoid subnormals)
        int id = (b - 16) * 256 + t;        // [0, 32768)
        int lam = id & 63, kk = (id >> 6) & 3, g = id >> 8;
        int n  = g * 32 + (lam & 31);
        int kb = kk * 16 + (lam >> 5) * 8;
        f16x8 v;
#pragma unroll
        for (int j = 0; j < 8; ++j)
            v[j] = (_Float16)(64.0f * E[(size_t)(kb + j) * CODES + n]);
        packed[id] = v;
    } else {
        if (!full) return;
        // ET = E^T (fp32) for the coalesced output gather
        int id = (b - 144) * 256 + t;       // [0, 65536)
        int j = id >> 4, i0 = (id & 15) * 4;
        float4 v;
        v.x = E[(size_t)(i0 + 0) * CODES + j];
        v.y = E[(size_t)(i0 + 1) * CODES + j];
        v.z = E[(size_t)(i0 + 2) * CODES + j];
        v.w = E[(size_t)(i0 + 3) * CODES + j];
        *(float4*)(ET + (size_t)j * EMBED + i0) = v;
    }
}

// Stage 1: per (row-group, code-half): partial top-2 over 2048 codes.
// acc = 256*x.e - 128*c = -128*score ; maximize.
__global__ __launch_bounds__(256, 4)
void vq_partial(const float* __restrict__ X, const float* __restrict__ cbuf,
                const f16x8* __restrict__ packed, float2* __restrict__ part_a,
                int* __restrict__ part_i) {
    __shared__ f16x8 lbuf[2][1024];         // 2 x 16 KB double buffer

    const int t  = threadIdx.x;
    const int l  = t & 63, wv = t >> 6;
    const int m  = l & 31, h  = l >> 5;
    const int rg   = blockIdx.x >> 1;       // row-group
    const int half = blockIdx.x & 1;        // code half
    const int row0 = rg * 128;

    // A fragments: fp16(4*x), persistent
    f16x8 ah[4];
    {
        const float* xrow = X + (size_t)(row0 + wv * 32 + m) * EMBED;
#pragma unroll
        for (int kk = 0; kk < 4; ++kk) {
            int kb = kk * 16 + h * 8;
            float4 v0 = *(const float4*)(xrow + kb);
            float4 v1 = *(const float4*)(xrow + kb + 4);
            float xv[8] = {v0.x, v0.y, v0.z, v0.w, v1.x, v1.y, v1.z, v1.w};
#pragma unroll
            for (int j = 0; j < 8; ++j) ah[kk][j] = (_Float16)(4.0f * xv[j]);
        }
    }

    float M1[16], M2[16];
#pragma unroll
    for (int e = 0; e < 16; ++e) { M1[e] = -FLT_MAX; M2[e] = -FLT_MAX; }

    auto stage = [&](int ch, int buf) {
#pragma unroll
        for (int q = 0; q < 4; ++q) {
            const f16x8* gp = packed + half * 16384 + ch * 1024 + q * 256 + t;
            f16x8* lp = &lbuf[buf][q * 256 + wv * 64];   // wave-uniform base + lane*16
            __builtin_amdgcn_global_load_lds(
                (const __attribute__((address_space(1))) void*)gp,
                (__attribute__((address_space(3))) void*)lp, 16, 0, 0);
        }
    };

    const int ch0 = rg & 15;                // rotate chunk order across blocks
    stage(ch0, 0);
    __syncthreads();

    int b = 0;
#pragma unroll 1
    for (int cc = 0; cc < 16; ++cc) {
        int ch = (ch0 + cc) & 15;
        if (cc + 1 < 16) stage((ch + 1) & 15, b ^ 1);
        const f16x8* lb = lbuf[b];
#pragma unroll
        for (int tl = 0; tl < 4; ++tl) {
            const int g = half * 64 + ch * 4 + tl;       // global tile id, 7 bits
            f16x8 Bf[4];
#pragma unroll
            for (int kk = 0; kk < 4; ++kk) Bf[kk] = lb[tl * 256 + kk * 64 + l];
            float nc = -128.0f * cbuf[g * 32 + m];
            f32x16 acc;
#pragma unroll
            for (int e = 0; e < 16; ++e) acc[e] = nc;
#pragma unroll
            for (int kk = 0; kk < 4; ++kk)
                acc = __builtin_amdgcn_mfma_f32_32x32x16_f16(ah[kk], Bf[kk], acc, 0, 0, 0);
            unsigned gu = (unsigned)g;
#pragma unroll
            for (int e = 0; e < 16; ++e) {
                float ap = __uint_as_float((__float_as_uint(acc[e]) & 0xFFFFFF80u) | gu);
                float m1o = M1[e];
                M1[e] = fmaxf(m1o, ap);
                M2[e] = __builtin_amdgcn_fmed3f(m1o, M2[e], ap);
            }
        }
        __syncthreads();
        b ^= 1;
    }

    // extract idx, cross-lane top-2 merge within each 32-lane half
    int I1[16];
#pragma unroll
    for (int e = 0; e < 16; ++e)
        I1[e] = (int)(((__float_as_uint(M1[e]) & 0x7Fu) << 5) | (unsigned)m);
#pragma unroll
    for (int d = 1; d < 32; d <<= 1) {
#pragma unroll
        for (int e = 0; e < 16; ++e) {
            float oM1 = __shfl_xor(M1[e], d, 64);
            float oM2 = __shfl_xor(M2[e], d, 64);
            int   oI  = __shfl_xor(I1[e], d, 64);
            float lo  = fminf(M1[e], oM1);
            M2[e] = fmaxf(lo, fmaxf(M2[e], oM2));
            bool c = oM1 > M1[e];
            I1[e] = c ? oI : I1[e];
            M1[e] = c ? oM1 : M1[e];
        }
    }
    // C/D row = (reg&3) + 8*(reg>>2) + 4*(lane>>5)
#pragma unroll
    for (int e = 0; e < 16; ++e) {
        int r = (e & 3) + 8 * (e >> 2) + 4 * h;
        if (m == r) {
            int gr = row0 + wv * 32 + r;
            part_a[half * NROWS + gr] = make_float2(M1[e], M2[e]);
            part_i[half * NROWS + gr] = I1[e];
        }
    }
}

// Stage 2: merge halves, exact fallback for near-ties, write idx/loss/quantized.
__global__ __launch_bounds__(256)
void vq_final(const float* __restrict__ X, const float* __restrict__ E,
              const float* __restrict__ cbuf, const float2* __restrict__ part_a,
              const int* __restrict__ part_i, const float* __restrict__ ET,
              double* __restrict__ accum, float* __restrict__ out) {
    __shared__ int   rowidx[128], rowflg[128];
    __shared__ float term[128];
    __shared__ float xsh[EMBED];
    __shared__ unsigned long long keysh[128];

    const int t = threadIdx.x;
    const int row0 = blockIdx.x * 128;

    if (t < 128) {
        int gr = row0 + t;
        float2 p0 = part_a[gr], p1 = part_a[NROWS + gr];
        int    j0 = part_i[gr], j1 = part_i[NROWS + gr];
        bool c = p1.x > p0.x;
        float M1 = c ? p1.x : p0.x;
        float M2 = fmaxf(c ? p0.x : p1.x, c ? p1.y : p0.y);
        rowidx[t] = c ? j1 : j0;
        rowflg[t] = ((M1 - M2) < 128.0f * TH) ? 1 : 0;
        keysh[t]  = ~0ull;
        float M1c = __uint_as_float(__float_as_uint(M1) & 0xFFFFFF80u);
        const float* xr = X + (size_t)gr * EMBED;
        float sq = 0.f;
#pragma unroll
        for (int i = 0; i < EMBED; ++i) sq = fmaf(xr[i], xr[i], sq);
        term[t] = sq - M1c * (1.0f / 128.0f);   // ||x||^2 + score_min
    }
    __syncthreads();

    // exact fallback: bit-exact fp32 numpy-reference emulation (uniform branch).
    // 16 interleaved sequential-FMA chains per thread (latency-pipelined);
    // argmin via monotone (d,j) key + LDS atomicMin.
#pragma unroll 1
    for (int r = 0; r < 128; ++r) {
        if (rowflg[r] == 0) continue;
        if (t < EMBED) xsh[t] = X[(size_t)(row0 + r) * EMBED + t];
        __syncthreads();

        // A: numpy pairwise sum of x*x (n=64: 8 accumulators + tree combine), uniform
        float racc[8];
#pragma unroll
        for (int jq = 0; jq < 8; ++jq) racc[jq] = __fmul_rn(xsh[jq], xsh[jq]);
#pragma unroll
        for (int i = 8; i < 64; i += 8)
#pragma unroll
            for (int jq = 0; jq < 8; ++jq)
                racc[jq] = __fadd_rn(racc[jq], __fmul_rn(xsh[i + jq], xsh[i + jq]));
        float A = __fadd_rn(
            __fadd_rn(__fadd_rn(racc[0], racc[1]), __fadd_rn(racc[2], racc[3])),
            __fadd_rn(__fadd_rn(racc[4], racc[5]), __fadd_rn(racc[6], racc[7])));

        float mmv[16];
#pragma unroll
        for (int jj = 0; jj < 16; ++jj) mmv[jj] = 0.f;
#pragma unroll 4
        for (int i = 0; i < 64; ++i) {
            float xi = xsh[i];
            const float* er = E + (size_t)i * CODES + t;
#pragma unroll
            for (int jj = 0; jj < 16; ++jj)
                mmv[jj] = fmaf(xi, er[jj * 256], mmv[jj]);   // sequential chain per code
        }
        unsigned long long bestk = ~0ull;
#pragma unroll
        for (int jj = 0; jj < 16; ++jj) {
            int j = jj * 256 + t;
            float d = __fadd_rn(__fsub_rn(A, __fmul_rn(2.f, mmv[jj])), cbuf[j]);
            unsigned ud = __float_as_uint(d);
            ud = (ud & 0x80000000u) ? ~ud : (ud | 0x80000000u);  // monotone float->uint
            unsigned long long key = ((unsigned long long)ud << 32) | (unsigned)j;
            bestk = key < bestk ? key : bestk;
        }
        atomicMin(&keysh[r], bestk);
        __syncthreads();
    }
    if (t < 128 && rowflg[t]) rowidx[t] = (int)(keysh[t] & 0xFFFFFFFFu);
    __syncthreads();

    // outputs
    if (t < 128) out[(size_t)NELEM + 1 + row0 + t] = (float)rowidx[t];  // idx as float
    if (t == 0) {
        float bs = 0.f;
        for (int r = 0; r < 128; ++r) bs += term[r];
        atomicAdd(accum, (double)bs);
    }
    {
        int r = t >> 1, i0 = (t & 1) * 32;
        int j = rowidx[r];
        float* dst = out + (size_t)(row0 + r) * EMBED + i0;
        const float* src = ET + (size_t)j * EMBED + i0;
#pragma unroll
        for (int g = 0; g < 8; ++g)
            *(float4*)(dst + g * 4) = *(const float4*)(src + g * 4);
    }
}

// Self-contained safety net if ws is too small: bf16 3-split, on-the-fly convert.
__global__ __launch_bounds__(256)
void vq_small(const float* __restrict__ X, const float* __restrict__ E,
              const float* __restrict__ cbuf, double* __restrict__ accum,
              float* __restrict__ out) {
    __shared__ float rowm1[128], rowsq[128];
    __shared__ int   rowidx[128], rowflg[128];
    __shared__ float xsh[EMBED];
    __shared__ unsigned long long keysh[128];

    const int t  = threadIdx.x;
    const int l  = t & 63, wv = t >> 6;
    const int m  = l & 31, h  = l >> 5;
    const int row0 = blockIdx.x * 128;

    bf16x8 ah[4], al[4];
    float sqreg;
    {
        const float* xrow = X + (size_t)(row0 + wv * 32 + m) * EMBED;
        float sq = 0.f;
#pragma unroll
        for (int kk = 0; kk < 4; ++kk) {
            int kb = kk * 16 + h * 8;
            float4 v0 = *(const float4*)(xrow + kb);
            float4 v1 = *(const float4*)(xrow + kb + 4);
            float xv[8] = {v0.x, v0.y, v0.z, v0.w, v1.x, v1.y, v1.z, v1.w};
#pragma unroll
            for (int j = 0; j < 8; ++j) {
                sq = fmaf(xv[j], xv[j], sq);
                unsigned short hi = f2bf(xv[j]);
                ah[kk][j] = (short)hi;
                al[kk][j] = (short)f2bf(xv[j] - bf2f(hi));
            }
        }
        sq += __shfl_xor(sq, 32, 64);
        sqreg = sq;
    }

    float M1[16], M2[16];
#pragma unroll
    for (int e = 0; e < 16; ++e) { M1[e] = -FLT_MAX; M2[e] = -FLT_MAX; }

#pragma unroll 1
    for (int g = 0; g < 128; ++g) {
        bf16x8 B[8];
        int n = g * 32 + m;
#pragma unroll
        for (int kk = 0; kk < 4; ++kk) {
            const float* ec = E + (size_t)(kk * 16 + h * 8) * CODES + n;
            bf16x8 vh, vl;
#pragma unroll
            for (int j = 0; j < 8; ++j) {
                float e = ec[(size_t)j * CODES];
                unsigned short hi = f2bf(e);
                vh[j] = (short)hi;
                vl[j] = (short)f2bf(e - bf2f(hi));
            }
            B[kk * 2] = vh; B[kk * 2 + 1] = vl;
        }
        float nc = -0.5f * cbuf[g * 32 + m];
        f32x16 acc;
#pragma unroll
        for (int e = 0; e < 16; ++e) acc[e] = nc;
#pragma unroll
        for (int kk = 0; kk < 4; ++kk) {
            acc = __builtin_amdgcn_mfma_f32_32x32x16_bf16(ah[kk], B[kk * 2],     acc, 0, 0, 0);
            acc = __builtin_amdgcn_mfma_f32_32x32x16_bf16(ah[kk], B[kk * 2 + 1], acc, 0, 0, 0);
            acc = __builtin_amdgcn_mfma_f32_32x32x16_bf16(al[kk], B[kk * 2],     acc, 0, 0, 0);
        }
        unsigned gu = (unsigned)g;
#pragma unroll
        for (int e = 0; e < 16; ++e) {
            float ap = __uint_as_float((__float_as_uint(acc[e]) & 0xFFFFFF80u) | gu);
            float m1o = M1[e];
            M1[e] = fmaxf(m1o, ap);
            M2[e] = __builtin_amdgcn_fmed3f(m1o, M2[e], ap);
        }
    }

    int I1[16];
#pragma unroll
    for (int e = 0; e < 16; ++e)
        I1[e] = (int)(((__float_as_uint(M1[e]) & 0x7Fu) << 5) | (unsigned)m);
#pragma unroll
    for (int d = 1; d < 32; d <<= 1) {
#pragma unroll
        for (int e = 0; e < 16; ++e) {
            float oM1 = __shfl_xor(M1[e], d, 64);
            float oM2 = __shfl_xor(M2[e], d, 64);
            int   oI  = __shfl_xor(I1[e], d, 64);
            float lo  = fminf(M1[e], oM1);
            M2[e] = fmaxf(lo, fmaxf(M2[e], oM2));
            bool c = oM1 > M1[e];
            I1[e] = c ? oI : I1[e];
            M1[e] = c ? oM1 : M1[e];
        }
    }
    if (h == 0) rowsq[wv * 32 + m] = sqreg;
#pragma unroll
    for (int e = 0; e < 16; ++e) {
        int r = (e & 3) + 8 * (e >> 2) + 4 * h;
        if (m == r) {
            rowm1[wv * 32 + r]  = __uint_as_float(__float_as_uint(M1[e]) & 0xFFFFFF80u);
            rowidx[wv * 32 + r] = I1[e];
            rowflg[wv * 32 + r] = (2.f * (M1[e] - M2[e]) < 2e-4f) ? 1 : 0;
        }
    }
    if (t < 128) keysh[t] = ~0ull;
    __syncthreads();

#pragma unroll 1
    for (int r = 0; r < 128; ++r) {
        if (rowflg[r] == 0) continue;
        if (t < EMBED) xsh[t] = X[(size_t)(row0 + r) * EMBED + t];
        __syncthreads();
        float racc[8];
#pragma unroll
        for (int jq = 0; jq < 8; ++jq) racc[jq] = __fmul_rn(xsh[jq], xsh[jq]);
#pragma unroll
        for (int i = 8; i < 64; i += 8)
#pragma unroll
            for (int jq = 0; jq < 8; ++jq)
                racc[jq] = __fadd_rn(racc[jq], __fmul_rn(xsh[i + jq], xsh[i + jq]));
        float A = __fadd_rn(
            __fadd_rn(__fadd_rn(racc[0], racc[1]), __fadd_rn(racc[2], racc[3])),
            __fadd_rn(__fadd_rn(racc[4], racc[5]), __fadd_rn(racc[6], racc[7])));
        float mmv[16];
#pragma unroll
        for (int jj = 0; jj < 16; ++jj) mmv[jj] = 0.f;
#pragma unroll 4
        for (int i = 0; i < 64; ++i) {
            float xi = xsh[i];
            const float* er = E + (size_t)i * CODES + t;
#pragma unroll
            for (int jj = 0; jj < 16; ++jj)
                mmv[jj] = fmaf(xi, er[jj * 256], mmv[jj]);
        }
        unsigned long long bestk = ~0ull;
#pragma unroll
        for (int jj = 0; jj < 16; ++jj) {
            int j = jj * 256 + t;
            float d = __fadd_rn(__fsub_rn(A, __fmul_rn(2.f, mmv[jj])), cbuf[j]);
            unsigned ud = __float_as_uint(d);
            ud = (ud & 0x80000000u) ? ~ud : (ud | 0x80000000u);
            unsigned long long key = ((unsigned long long)ud << 32) | (unsigned)j;
            bestk = key < bestk ? key : bestk;
        }
        atomicMin(&keysh[r], bestk);
        __syncthreads();
    }
    if (t < 128 && rowflg[t]) rowidx[t] = (int)(keysh[t] & 0xFFFFFFFFu);
    __syncthreads();

    if (t < 128) out[(size_t)NELEM + 1 + row0 + t] = (float)rowidx[t];
    if (t == 0) {
        float bs = 0.f;
        for (int r = 0; r < 128; ++r) bs += rowsq[r] - 2.f * rowm1[r];
        atomicAdd(accum, (double)bs);
    }
    {
        int r = t >> 1, i0 = (t & 1) * 32;
        int j = rowidx[r];
        float* dst = out + (size_t)(row0 + r) * EMBED + i0;
#pragma unroll
        for (int g = 0; g < 8; ++g) {
            float4 v;
            v.x = E[(size_t)(i0 + g * 4 + 0) * CODES + j];
            v.y = E[(size_t)(i0 + g * 4 + 1) * CODES + j];
            v.z = E[(size_t)(i0 + g * 4 + 2) * CODES + j];
            v.w = E[(size_t)(i0 + g * 4 + 3) * CODES + j];
            *(float4*)(dst + g * 4) = v;
        }
    }
}

__global__ void vq_finalize(const double* __restrict__ accum, float* __restrict__ out) {
    out[NELEM] = (float)(0.25 * (*accum) / (double)NELEM);
}

extern "C" void kernel_launch(void* const* d_in, const int* in_sizes, int n_in,
                              void* d_out, int out_size, void* d_ws, size_t ws_size,
                              hipStream_t stream) {
    const float* X = (const float*)d_in[0];   // (512, 8192, 1) f32 -> 65536 rows x 64
    const float* E = (const float*)d_in[1];   // (64, 4096) f32 row-major
    float* out = (float*)d_out;
    float*  cbuf   = (float*)d_ws;
    double* accum  = (double*)((char*)d_ws + 16384);
    f16x8*  packed = (f16x8*)((char*)d_ws + WS_PACKED);
    float*  ET     = (float*)((char*)d_ws + WS_ET);
    float2* part_a = (float2*)((char*)d_ws + WS_PARTA);
    int*    part_i = (int*)((char*)d_ws + WS_PARTI);
    const bool big = (ws_size >= WS_NEED);    // constant across calls -> same work every call

    vq_setup<<<big ? 400 : 16, 256, 0, stream>>>(E, cbuf, accum, packed, ET, big ? 1 : 0);
    if (big) {
        vq_partial<<<1024, 256, 0, stream>>>(X, cbuf, packed, part_a, part_i);
        vq_final<<<512, 256, 0, stream>>>(X, E, cbuf, part_a, part_i, ET, accum, out);
    } else {
        vq_small<<<512, 256, 0, stream>>>(X, E, cbuf, accum, out);
    }
    vq_finalize<<<1, 1, 0, stream>>>(accum, out);
}

// Round 9
// 459.282 us; speedup vs baseline: 2.7243x; 1.3093x over previous
//
#include <hip/hip_runtime.h>
#include <float.h>

#define EMBED   64
#define CODES   4096
#define NROWS   65536      // 512*8192/64
#define NELEM   4194304    // 512*8192
#define TH      6e-4f      // score-gap flag threshold (fp16 2-product budget, ~7 sigma)

typedef __attribute__((ext_vector_type(8)))  _Float16 f16x8;  // 8 fp16 in 4 VGPRs
typedef __attribute__((ext_vector_type(8)))  short bf16x8;    // 8 bf16 (small-ws path)
typedef __attribute__((ext_vector_type(16))) float f32x16;    // MFMA 32x32 accumulator

__device__ inline unsigned short f2bf(float f) {              // RNE float->bf16
    unsigned u = __float_as_uint(f);
    u += 0x7fff + ((u >> 16) & 1);
    return (unsigned short)(u >> 16);
}
__device__ inline float bf2f(unsigned short h) {
    return __uint_as_float(((unsigned)h) << 16);
}

// ws: [0,16K) cbuf fp32; [16K] double accum; [32K,+512K) packed f16 B-frags;
//     [557056,+1M) ET fp32; [1605632] part_a float2[np*NROWS]; then part_i int[np*NROWS]
#define WS_PACKED   32768
#define WS_ET       557056
#define WS_PARTA    1605632

// Fused setup: blocks 0..15 cbuf(+accum), 16..143 pack f16 (e*64), 144..399 ET.
__global__ void vq_setup(const float* __restrict__ E, float* __restrict__ cbuf,
                         double* __restrict__ accum, f16x8* __restrict__ packed,
                         float* __restrict__ ET, int full) {
    const int b = blockIdx.x, t = threadIdx.x;
    if (b < 16) {
        // cbuf: emulate np.sum(E*E, axis=0) (C-order: sequential i, mul/add rounded)
        int j = b * 256 + t;
        float v = E[j];
        float s = __fmul_rn(v, v);
        for (int i = 1; i < EMBED; ++i) {
            v = E[(size_t)i * CODES + j];
            s = __fadd_rn(s, __fmul_rn(v, v));
        }
        cbuf[j] = s;
        if (j == 0) *accum = 0.0;           // d_ws poisoned 0xAA before every launch
    } else if (b < 144) {
        if (!full) return;
        // pack E into MFMA B-fragment order, fp16, scaled by 64 (avoid subnormals)
        int id = (b - 16) * 256 + t;        // [0, 32768)
        int lam = id & 63, kk = (id >> 6) & 3, g = id >> 8;
        int n  = g * 32 + (lam & 31);
        int kb = kk * 16 + (lam >> 5) * 8;
        f16x8 v;
#pragma unroll
        for (int j = 0; j < 8; ++j)
            v[j] = (_Float16)(64.0f * E[(size_t)(kb + j) * CODES + n]);
        packed[id] = v;
    } else {
        if (!full) return;
        // ET = E^T (fp32) for the exact fallback + coalesced output gather
        int id = (b - 144) * 256 + t;       // [0, 65536)
        int j = id >> 4, i0 = (id & 15) * 4;
        float4 v;
        v.x = E[(size_t)(i0 + 0) * CODES + j];
        v.y = E[(size_t)(i0 + 1) * CODES + j];
        v.z = E[(size_t)(i0 + 2) * CODES + j];
        v.w = E[(size_t)(i0 + 3) * CODES + j];
        *(float4*)(ET + (size_t)j * EMBED + i0) = v;
    }
}

// Stage 1: per (row-group, code-part): partial top-2 over 4096>>npl codes.
// acc = 256*x.e - 128*c = -128*score (2-product fp16: x = xh+xl) ; maximize.
__global__ __launch_bounds__(256, 4)
void vq_partial(const float* __restrict__ X, const float* __restrict__ cbuf,
                const f16x8* __restrict__ packed, float2* __restrict__ part_a,
                int* __restrict__ part_i, int npl) {
    __shared__ f16x8 lbuf[2][1024];         // 2 x 16 KB double buffer (4 tiles/chunk)

    const int t  = threadIdx.x;
    const int l  = t & 63, wv = t >> 6;
    const int m  = l & 31, h  = l >> 5;
    const int p    = blockIdx.x & ((1 << npl) - 1);
    const int rg   = blockIdx.x >> npl;
    const int row0 = rg * 128;
    const int tpp    = 128 >> npl;          // tiles per part
    const int chunks = tpp >> 2;

    // A fragments: fp16 2-split of 4*x, persistent
    f16x8 ah[4], al[4];
    {
        const float* xrow = X + (size_t)(row0 + wv * 32 + m) * EMBED;
#pragma unroll
        for (int kk = 0; kk < 4; ++kk) {
            int kb = kk * 16 + h * 8;
            float4 v0 = *(const float4*)(xrow + kb);
            float4 v1 = *(const float4*)(xrow + kb + 4);
            float xv[8] = {v0.x, v0.y, v0.z, v0.w, v1.x, v1.y, v1.z, v1.w};
#pragma unroll
            for (int j = 0; j < 8; ++j) {
                float s = 4.0f * xv[j];
                _Float16 hi = (_Float16)s;
                ah[kk][j] = hi;
                al[kk][j] = (_Float16)(s - (float)hi);
            }
        }
    }

    float M1[16], M2[16];
#pragma unroll
    for (int e = 0; e < 16; ++e) { M1[e] = -FLT_MAX; M2[e] = -FLT_MAX; }

    auto stage = [&](int ch, int buf) {
#pragma unroll
        for (int q = 0; q < 4; ++q) {
            const f16x8* gp = packed + (p * tpp + ch * 4) * 256 + q * 256 + t;
            f16x8* lp = &lbuf[buf][q * 256 + wv * 64];   // wave-uniform base + lane*16
            __builtin_amdgcn_global_load_lds(
                (const __attribute__((address_space(1))) void*)gp,
                (__attribute__((address_space(3))) void*)lp, 16, 0, 0);
        }
    };

    const int ch0 = rg & (chunks - 1);      // rotate chunk order across blocks
    stage(ch0, 0);
    __syncthreads();

    int b = 0;
#pragma unroll 1
    for (int cc = 0; cc < chunks; ++cc) {
        int ch = (ch0 + cc) & (chunks - 1);
        if (cc + 1 < chunks) stage((ch + 1) & (chunks - 1), b ^ 1);
        const f16x8* lb = lbuf[b];
#pragma unroll
        for (int tl = 0; tl < 4; ++tl) {
            const int g = p * tpp + ch * 4 + tl;         // global tile id, 7 bits
            f16x8 Bf[4];
#pragma unroll
            for (int kk = 0; kk < 4; ++kk) Bf[kk] = lb[tl * 256 + kk * 64 + l];
            float nc = -128.0f * cbuf[g * 32 + m];
            f32x16 acc;
#pragma unroll
            for (int e = 0; e < 16; ++e) acc[e] = nc;
#pragma unroll
            for (int kk = 0; kk < 4; ++kk) {             // 2 products, same B fragment
                acc = __builtin_amdgcn_mfma_f32_32x32x16_f16(al[kk], Bf[kk], acc, 0, 0, 0);
                acc = __builtin_amdgcn_mfma_f32_32x32x16_f16(ah[kk], Bf[kk], acc, 0, 0, 0);
            }
            unsigned gu = (unsigned)g;
#pragma unroll
            for (int e = 0; e < 16; ++e) {
                float ap = __uint_as_float((__float_as_uint(acc[e]) & 0xFFFFFF80u) | gu);
                float m1o = M1[e];
                M1[e] = fmaxf(m1o, ap);
                M2[e] = __builtin_amdgcn_fmed3f(m1o, M2[e], ap);
            }
        }
        __syncthreads();
        b ^= 1;
    }

    // extract idx, cross-lane top-2 merge within each 32-lane half
    int I1[16];
#pragma unroll
    for (int e = 0; e < 16; ++e)
        I1[e] = (int)(((__float_as_uint(M1[e]) & 0x7Fu) << 5) | (unsigned)m);
#pragma unroll
    for (int d = 1; d < 32; d <<= 1) {
#pragma unroll
        for (int e = 0; e < 16; ++e) {
            float oM1 = __shfl_xor(M1[e], d, 64);
            float oM2 = __shfl_xor(M2[e], d, 64);
            int   oI  = __shfl_xor(I1[e], d, 64);
            float lo  = fminf(M1[e], oM1);
            M2[e] = fmaxf(lo, fmaxf(M2[e], oM2));
            bool c = oM1 > M1[e];
            I1[e] = c ? oI : I1[e];
            M1[e] = c ? oM1 : M1[e];
        }
    }
    // C/D row = (reg&3) + 8*(reg>>2) + 4*(lane>>5)
#pragma unroll
    for (int e = 0; e < 16; ++e) {
        int r = (e & 3) + 8 * (e >> 2) + 4 * h;
        if (m == r) {
            int gr = row0 + wv * 32 + r;
            part_a[p * NROWS + gr] = make_float2(M1[e], M2[e]);
            part_i[p * NROWS + gr] = I1[e];
        }
    }
}

// Stage 2: merge parts, exact fallback for near-ties, write idx/loss/quantized.
__global__ __launch_bounds__(256, 2)
void vq_final(const float* __restrict__ X, const float* __restrict__ cbuf,
              const float2* __restrict__ part_a, const int* __restrict__ part_i,
              const float* __restrict__ ET, double* __restrict__ accum,
              float* __restrict__ out, int np) {
    __shared__ int   rowidx[128], rowflg[128];
    __shared__ float term[128];
    __shared__ float xsh[EMBED];
    __shared__ unsigned long long keysh[128];

    const int t = threadIdx.x;
    const int row0 = blockIdx.x * 128;

    if (t < 128) {
        int gr = row0 + t;
        float M1 = -FLT_MAX, M2 = -FLT_MAX; int bi = 0;
        for (int p = 0; p < np; ++p) {
            float2 pa = part_a[p * NROWS + gr];
            int    pj = part_i[p * NROWS + gr];
            if (pa.x > M1) { M2 = fmaxf(M1, pa.y); M1 = pa.x; bi = pj; }
            else           { M2 = fmaxf(M2, pa.x); }
        }
        rowidx[t] = bi;
        rowflg[t] = ((M1 - M2) < 128.0f * TH) ? 1 : 0;
        keysh[t]  = ~0ull;
        float M1c = __uint_as_float(__float_as_uint(M1) & 0xFFFFFF80u);
        const float4* xr4 = (const float4*)(X + (size_t)gr * EMBED);
        float sq = 0.f;
#pragma unroll
        for (int q = 0; q < 16; ++q) {
            float4 v = xr4[q];
            sq = fmaf(v.x, v.x, sq); sq = fmaf(v.y, v.y, sq);
            sq = fmaf(v.z, v.z, sq); sq = fmaf(v.w, v.w, sq);
        }
        term[t] = sq - M1c * (1.0f / 128.0f);   // ||x||^2 + score_min
    }
    __syncthreads();

    // exact fallback: bit-exact fp32 numpy-reference emulation (uniform branch).
    // Per code: contiguous ET row via 16 independent float4 loads (pipelined),
    // then the sequential fmaf chain (BLAS k-loop order). argmin via (d,j) key.
#pragma unroll 1
    for (int r = 0; r < 128; ++r) {
        if (rowflg[r] == 0) continue;
        if (t < EMBED) xsh[t] = X[(size_t)(row0 + r) * EMBED + t];
        __syncthreads();

        // A: numpy pairwise sum of x*x (n=64: 8 accumulators + tree combine), uniform
        float racc[8];
#pragma unroll
        for (int jq = 0; jq < 8; ++jq) racc[jq] = __fmul_rn(xsh[jq], xsh[jq]);
#pragma unroll
        for (int i = 8; i < 64; i += 8)
#pragma unroll
            for (int jq = 0; jq < 8; ++jq)
                racc[jq] = __fadd_rn(racc[jq], __fmul_rn(xsh[i + jq], xsh[i + jq]));
        float A = __fadd_rn(
            __fadd_rn(__fadd_rn(racc[0], racc[1]), __fadd_rn(racc[2], racc[3])),
            __fadd_rn(__fadd_rn(racc[4], racc[5]), __fadd_rn(racc[6], racc[7])));

        unsigned long long bestk = ~0ull;
#pragma unroll 1
        for (int jj = 0; jj < 16; ++jj) {
            int j = jj * 256 + t;
            const float4* er = (const float4*)(ET + (size_t)j * EMBED);
            float4 w[16];
#pragma unroll
            for (int q = 0; q < 16; ++q) w[q] = er[q];   // independent, pipeline
            float mm = 0.f;
#pragma unroll
            for (int q = 0; q < 16; ++q) {               // strict i=0..63 order
                mm = fmaf(xsh[q * 4 + 0], w[q].x, mm);
                mm = fmaf(xsh[q * 4 + 1], w[q].y, mm);
                mm = fmaf(xsh[q * 4 + 2], w[q].z, mm);
                mm = fmaf(xsh[q * 4 + 3], w[q].w, mm);
            }
            float d = __fadd_rn(__fsub_rn(A, __fmul_rn(2.f, mm)), cbuf[j]);
            unsigned ud = __float_as_uint(d);
            ud = (ud & 0x80000000u) ? ~ud : (ud | 0x80000000u);  // monotone float->uint
            unsigned long long key = ((unsigned long long)ud << 32) | (unsigned)j;
            bestk = key < bestk ? key : bestk;
        }
        atomicMin(&keysh[r], bestk);
        __syncthreads();
    }
    if (t < 128 && rowflg[t]) rowidx[t] = (int)(keysh[t] & 0xFFFFFFFFu);
    __syncthreads();

    // outputs
    if (t < 128) out[(size_t)NELEM + 1 + row0 + t] = (float)rowidx[t];  // idx as float
    if (t == 0) {
        float bs = 0.f;
        for (int r = 0; r < 128; ++r) bs += term[r];
        atomicAdd(accum, (double)bs);
    }
    {
        int r = t >> 1, i0 = (t & 1) * 32;
        int j = rowidx[r];
        float* dst = out + (size_t)(row0 + r) * EMBED + i0;
        const float* src = ET + (size_t)j * EMBED + i0;
#pragma unroll
        for (int g = 0; g < 8; ++g)
            *(float4*)(dst + g * 4) = *(const float4*)(src + g * 4);
    }
}

// Self-contained safety net if ws is too small: bf16 3-split, on-the-fly convert.
__global__ __launch_bounds__(256)
void vq_small(const float* __restrict__ X, const float* __restrict__ E,
              const float* __restrict__ cbuf, double* __restrict__ accum,
              float* __restrict__ out) {
    __shared__ float rowm1[128], rowsq[128];
    __shared__ int   rowidx[128], rowflg[128];
    __shared__ float xsh[EMBED];
    __shared__ unsigned long long keysh[128];

    const int t  = threadIdx.x;
    const int l  = t & 63, wv = t >> 6;
    const int m  = l & 31, h  = l >> 5;
    const int row0 = blockIdx.x * 128;

    bf16x8 ah[4], al[4];
    float sqreg;
    {
        const float* xrow = X + (size_t)(row0 + wv * 32 + m) * EMBED;
        float sq = 0.f;
#pragma unroll
        for (int kk = 0; kk < 4; ++kk) {
            int kb = kk * 16 + h * 8;
            float4 v0 = *(const float4*)(xrow + kb);
            float4 v1 = *(const float4*)(xrow + kb + 4);
            float xv[8] = {v0.x, v0.y, v0.z, v0.w, v1.x, v1.y, v1.z, v1.w};
#pragma unroll
            for (int j = 0; j < 8; ++j) {
                sq = fmaf(xv[j], xv[j], sq);
                unsigned short hi = f2bf(xv[j]);
                ah[kk][j] = (short)hi;
                al[kk][j] = (short)f2bf(xv[j] - bf2f(hi));
            }
        }
        sq += __shfl_xor(sq, 32, 64);
        sqreg = sq;
    }

    float M1[16], M2[16];
#pragma unroll
    for (int e = 0; e < 16; ++e) { M1[e] = -FLT_MAX; M2[e] = -FLT_MAX; }

#pragma unroll 1
    for (int g = 0; g < 128; ++g) {
        bf16x8 B[8];
        int n = g * 32 + m;
#pragma unroll
        for (int kk = 0; kk < 4; ++kk) {
            const float* ec = E + (size_t)(kk * 16 + h * 8) * CODES + n;
            bf16x8 vh, vl;
#pragma unroll
            for (int j = 0; j < 8; ++j) {
                float e = ec[(size_t)j * CODES];
                unsigned short hi = f2bf(e);
                vh[j] = (short)hi;
                vl[j] = (short)f2bf(e - bf2f(hi));
            }
            B[kk * 2] = vh; B[kk * 2 + 1] = vl;
        }
        float nc = -0.5f * cbuf[g * 32 + m];
        f32x16 acc;
#pragma unroll
        for (int e = 0; e < 16; ++e) acc[e] = nc;
#pragma unroll
        for (int kk = 0; kk < 4; ++kk) {
            acc = __builtin_amdgcn_mfma_f32_32x32x16_bf16(ah[kk], B[kk * 2],     acc, 0, 0, 0);
            acc = __builtin_amdgcn_mfma_f32_32x32x16_bf16(ah[kk], B[kk * 2 + 1], acc, 0, 0, 0);
            acc = __builtin_amdgcn_mfma_f32_32x32x16_bf16(al[kk], B[kk * 2],     acc, 0, 0, 0);
        }
        unsigned gu = (unsigned)g;
#pragma unroll
        for (int e = 0; e < 16; ++e) {
            float ap = __uint_as_float((__float_as_uint(acc[e]) & 0xFFFFFF80u) | gu);
            float m1o = M1[e];
            M1[e] = fmaxf(m1o, ap);
            M2[e] = __builtin_amdgcn_fmed3f(m1o, M2[e], ap);
        }
    }

    int I1[16];
#pragma unroll
    for (int e = 0; e < 16; ++e)
        I1[e] = (int)(((__float_as_uint(M1[e]) & 0x7Fu) << 5) | (unsigned)m);
#pragma unroll
    for (int d = 1; d < 32; d <<= 1) {
#pragma unroll
        for (int e = 0; e < 16; ++e) {
            float oM1 = __shfl_xor(M1[e], d, 64);
            float oM2 = __shfl_xor(M2[e], d, 64);
            int   oI  = __shfl_xor(I1[e], d, 64);
            float lo  = fminf(M1[e], oM1);
            M2[e] = fmaxf(lo, fmaxf(M2[e], oM2));
            bool c = oM1 > M1[e];
            I1[e] = c ? oI : I1[e];
            M1[e] = c ? oM1 : M1[e];
        }
    }
    if (h == 0) rowsq[wv * 32 + m] = sqreg;
#pragma unroll
    for (int e = 0; e < 16; ++e) {
        int r = (e & 3) + 8 * (e >> 2) + 4 * h;
        if (m == r) {
            rowm1[wv * 32 + r]  = __uint_as_float(__float_as_uint(M1[e]) & 0xFFFFFF80u);
            rowidx[wv * 32 + r] = I1[e];
            rowflg[wv * 32 + r] = (2.f * (M1[e] - M2[e]) < 2e-4f) ? 1 : 0;
        }
    }
    if (t < 128) keysh[t] = ~0ull;
    __syncthreads();

#pragma unroll 1
    for (int r = 0; r < 128; ++r) {
        if (rowflg[r] == 0) continue;
        if (t < EMBED) xsh[t] = X[(size_t)(row0 + r) * EMBED + t];
        __syncthreads();
        float racc[8];
#pragma unroll
        for (int jq = 0; jq < 8; ++jq) racc[jq] = __fmul_rn(xsh[jq], xsh[jq]);
#pragma unroll
        for (int i = 8; i < 64; i += 8)
#pragma unroll
            for (int jq = 0; jq < 8; ++jq)
                racc[jq] = __fadd_rn(racc[jq], __fmul_rn(xsh[i + jq], xsh[i + jq]));
        float A = __fadd_rn(
            __fadd_rn(__fadd_rn(racc[0], racc[1]), __fadd_rn(racc[2], racc[3])),
            __fadd_rn(__fadd_rn(racc[4], racc[5]), __fadd_rn(racc[6], racc[7])));
        float mmv[16];
#pragma unroll
        for (int jj = 0; jj < 16; ++jj) mmv[jj] = 0.f;
#pragma unroll 4
        for (int i = 0; i < 64; ++i) {
            float xi = xsh[i];
            const float* er = E + (size_t)i * CODES + t;
#pragma unroll
            for (int jj = 0; jj < 16; ++jj)
                mmv[jj] = fmaf(xi, er[jj * 256], mmv[jj]);
        }
        unsigned long long bestk = ~0ull;
#pragma unroll
        for (int jj = 0; jj < 16; ++jj) {
            int j = jj * 256 + t;
            float d = __fadd_rn(__fsub_rn(A, __fmul_rn(2.f, mmv[jj])), cbuf[j]);
            unsigned ud = __float_as_uint(d);
            ud = (ud & 0x80000000u) ? ~ud : (ud | 0x80000000u);
            unsigned long long key = ((unsigned long long)ud << 32) | (unsigned)j;
            bestk = key < bestk ? key : bestk;
        }
        atomicMin(&keysh[r], bestk);
        __syncthreads();
    }
    if (t < 128 && rowflg[t]) rowidx[t] = (int)(keysh[t] & 0xFFFFFFFFu);
    __syncthreads();

    if (t < 128) out[(size_t)NELEM + 1 + row0 + t] = (float)rowidx[t];
    if (t == 0) {
        float bs = 0.f;
        for (int r = 0; r < 128; ++r) bs += rowsq[r] - 2.f * rowm1[r];
        atomicAdd(accum, (double)bs);
    }
    {
        int r = t >> 1, i0 = (t & 1) * 32;
        int j = rowidx[r];
        float* dst = out + (size_t)(row0 + r) * EMBED + i0;
#pragma unroll
        for (int g = 0; g < 8; ++g) {
            float4 v;
            v.x = E[(size_t)(i0 + g * 4 + 0) * CODES + j];
            v.y = E[(size_t)(i0 + g * 4 + 1) * CODES + j];
            v.z = E[(size_t)(i0 + g * 4 + 2) * CODES + j];
            v.w = E[(size_t)(i0 + g * 4 + 3) * CODES + j];
            *(float4*)(dst + g * 4) = v;
        }
    }
}

__global__ void vq_finalize(const double* __restrict__ accum, float* __restrict__ out) {
    out[NELEM] = (float)(0.25 * (*accum) / (double)NELEM);
}

extern "C" void kernel_launch(void* const* d_in, const int* in_sizes, int n_in,
                              void* d_out, int out_size, void* d_ws, size_t ws_size,
                              hipStream_t stream) {
    const float* X = (const float*)d_in[0];   // (512, 8192, 1) f32 -> 65536 rows x 64
    const float* E = (const float*)d_in[1];   // (64, 4096) f32 row-major
    float* out = (float*)d_out;
    float*  cbuf   = (float*)d_ws;
    double* accum  = (double*)((char*)d_ws + 16384);
    f16x8*  packed = (f16x8*)((char*)d_ws + WS_PACKED);
    float*  ET     = (float*)((char*)d_ws + WS_ET);
    float2* part_a = (float2*)((char*)d_ws + WS_PARTA);

    // npl=2 (quarters) needs 4.53 MB; npl=1 (halves) needs 3.18 MB; else small path
    int npl = 0;
    if (ws_size >= (size_t)WS_PARTA + 4u * NROWS * 12u)      npl = 2;
    else if (ws_size >= (size_t)WS_PARTA + 2u * NROWS * 12u) npl = 1;
    const bool big = (npl > 0);
    const int  np  = 1 << npl;
    int* part_i = (int*)((char*)d_ws + WS_PARTA + (size_t)np * NROWS * 8u);

    vq_setup<<<big ? 400 : 16, 256, 0, stream>>>(E, cbuf, accum, packed, ET, big ? 1 : 0);
    if (big) {
        vq_partial<<<512 << npl, 256, 0, stream>>>(X, cbuf, packed, part_a, part_i, npl);
        vq_final<<<512, 256, 0, stream>>>(X, cbuf, part_a, part_i, ET, accum, out, np);
    } else {
        vq_small<<<512, 256, 0, stream>>>(X, E, cbuf, accum, out);
    }
    vq_finalize<<<1, 1, 0, stream>>>(accum, out);
}

// Round 10
// 280.120 us; speedup vs baseline: 4.4668x; 1.6396x over previous
//
#include <hip/hip_runtime.h>
#include <float.h>

#define EMBED   64
#define CODES   4096
#define NROWS   65536      // 512*8192/64
#define NELEM   4194304    // 512*8192
#define TH      6e-4f      // score-gap flag threshold (fp16 2-product budget, ~8 sigma)

typedef __attribute__((ext_vector_type(8)))  _Float16 f16x8;  // 8 fp16 in 4 VGPRs
typedef __attribute__((ext_vector_type(8)))  short bf16x8;    // 8 bf16 (small-ws path)
typedef __attribute__((ext_vector_type(16))) float f32x16;    // MFMA 32x32 accumulator

__device__ inline unsigned short f2bf(float f) {              // RNE float->bf16
    unsigned u = __float_as_uint(f);
    u += 0x7fff + ((u >> 16) & 1);
    return (unsigned short)(u >> 16);
}
__device__ inline float bf2f(unsigned short h) {
    return __uint_as_float(((unsigned)h) << 16);
}

// ws: [0,16K) cbuf; [16384] accum double; [16392] list_cnt int; [32K,+512K) packed;
//     [557056,+1M) ET; [1605632,+256K) flag list; [1867776..) part_a then part_i
#define WS_ACCUM    16384
#define WS_LISTCNT  16392
#define WS_PACKED   32768
#define WS_ET       557056
#define WS_LIST     1605632
#define WS_PART     1867776

// Fused setup: blocks 0..15 cbuf(+accum+list_cnt), 16..143 pack f16 (e*64), 144..399 ET.
__global__ void vq_setup(const float* __restrict__ E, float* __restrict__ cbuf,
                         double* __restrict__ accum, int* __restrict__ list_cnt,
                         f16x8* __restrict__ packed, float* __restrict__ ET, int full) {
    const int b = blockIdx.x, t = threadIdx.x;
    if (b < 16) {
        // cbuf: emulate np.sum(E*E, axis=0) (C-order: sequential i, mul/add rounded)
        int j = b * 256 + t;
        float v = E[j];
        float s = __fmul_rn(v, v);
        for (int i = 1; i < EMBED; ++i) {
            v = E[(size_t)i * CODES + j];
            s = __fadd_rn(s, __fmul_rn(v, v));
        }
        cbuf[j] = s;
        if (j == 0) *accum = 0.0;           // d_ws poisoned 0xAA before every launch
        if (j == 1) *list_cnt = 0;
    } else if (b < 144) {
        if (!full) return;
        // pack E into MFMA B-fragment order, fp16, scaled by 64 (avoid subnormals)
        int id = (b - 16) * 256 + t;        // [0, 32768)
        int lam = id & 63, kk = (id >> 6) & 3, g = id >> 8;
        int n  = g * 32 + (lam & 31);
        int kb = kk * 16 + (lam >> 5) * 8;
        f16x8 v;
#pragma unroll
        for (int j = 0; j < 8; ++j)
            v[j] = (_Float16)(64.0f * E[(size_t)(kb + j) * CODES + n]);
        packed[id] = v;
    } else {
        if (!full) return;
        // ET = E^T (fp32) for the coalesced output gather
        int id = (b - 144) * 256 + t;       // [0, 65536)
        int j = id >> 4, i0 = (id & 15) * 4;
        float4 v;
        v.x = E[(size_t)(i0 + 0) * CODES + j];
        v.y = E[(size_t)(i0 + 1) * CODES + j];
        v.z = E[(size_t)(i0 + 2) * CODES + j];
        v.w = E[(size_t)(i0 + 3) * CODES + j];
        *(float4*)(ET + (size_t)j * EMBED + i0) = v;
    }
}

// Stage 1: per (row-group, code-part): partial top-2 over 4096>>npl codes.
// acc = 256*x.e - 128*c = -128*score (2-product fp16: x = xh+xl) ; maximize.
__global__ __launch_bounds__(256, 4)
void vq_partial(const float* __restrict__ X, const float* __restrict__ cbuf,
                const f16x8* __restrict__ packed, float2* __restrict__ part_a,
                int* __restrict__ part_i, int npl) {
    __shared__ f16x8 lbuf[2][1024];         // 2 x 16 KB double buffer (4 tiles/chunk)

    const int t  = threadIdx.x;
    const int l  = t & 63, wv = t >> 6;
    const int m  = l & 31, h  = l >> 5;
    const int p    = blockIdx.x & ((1 << npl) - 1);
    const int rg   = blockIdx.x >> npl;
    const int row0 = rg * 128;
    const int tpp    = 128 >> npl;          // tiles per part
    const int chunks = tpp >> 2;

    // A fragments: fp16 2-split of 4*x, persistent
    f16x8 ah[4], al[4];
    {
        const float* xrow = X + (size_t)(row0 + wv * 32 + m) * EMBED;
#pragma unroll
        for (int kk = 0; kk < 4; ++kk) {
            int kb = kk * 16 + h * 8;
            float4 v0 = *(const float4*)(xrow + kb);
            float4 v1 = *(const float4*)(xrow + kb + 4);
            float xv[8] = {v0.x, v0.y, v0.z, v0.w, v1.x, v1.y, v1.z, v1.w};
#pragma unroll
            for (int j = 0; j < 8; ++j) {
                float s = 4.0f * xv[j];
                _Float16 hi = (_Float16)s;
                ah[kk][j] = hi;
                al[kk][j] = (_Float16)(s - (float)hi);
            }
        }
    }

    float M1[16], M2[16];
#pragma unroll
    for (int e = 0; e < 16; ++e) { M1[e] = -FLT_MAX; M2[e] = -FLT_MAX; }

    auto stage = [&](int ch, int buf) {
#pragma unroll
        for (int q = 0; q < 4; ++q) {
            const f16x8* gp = packed + (p * tpp + ch * 4) * 256 + q * 256 + t;
            f16x8* lp = &lbuf[buf][q * 256 + wv * 64];   // wave-uniform base + lane*16
            __builtin_amdgcn_global_load_lds(
                (const __attribute__((address_space(1))) void*)gp,
                (__attribute__((address_space(3))) void*)lp, 16, 0, 0);
        }
    };

    const int ch0 = rg & (chunks - 1);      // rotate chunk order across blocks
    float ncc[4], ncn[4];
#pragma unroll
    for (int tl = 0; tl < 4; ++tl)          // prefetch chunk 0's nc before barrier
        ncc[tl] = -128.0f * cbuf[(p * tpp + ch0 * 4 + tl) * 32 + m];
    stage(ch0, 0);
    __syncthreads();

    int b = 0;
#pragma unroll 1
    for (int cc = 0; cc < chunks; ++cc) {
        int ch = (ch0 + cc) & (chunks - 1);
        if (cc + 1 < chunks) {
            int cn = (ch + 1) & (chunks - 1);
            stage(cn, b ^ 1);
#pragma unroll
            for (int tl = 0; tl < 4; ++tl)  // prefetch next chunk's nc (hidden)
                ncn[tl] = -128.0f * cbuf[(p * tpp + cn * 4 + tl) * 32 + m];
        }
        const f16x8* lb = lbuf[b];
#pragma unroll
        for (int tl = 0; tl < 4; ++tl) {
            const int g = p * tpp + ch * 4 + tl;         // global tile id, 7 bits
            f16x8 Bf[4];
#pragma unroll
            for (int kk = 0; kk < 4; ++kk) Bf[kk] = lb[tl * 256 + kk * 64 + l];
            f32x16 acc;
#pragma unroll
            for (int e = 0; e < 16; ++e) acc[e] = ncc[tl];
#pragma unroll
            for (int kk = 0; kk < 4; ++kk) {             // 2 products, same B fragment
                acc = __builtin_amdgcn_mfma_f32_32x32x16_f16(al[kk], Bf[kk], acc, 0, 0, 0);
                acc = __builtin_amdgcn_mfma_f32_32x32x16_f16(ah[kk], Bf[kk], acc, 0, 0, 0);
            }
            unsigned gu = (unsigned)g;
#pragma unroll
            for (int e = 0; e < 16; ++e) {
                float ap = __uint_as_float((__float_as_uint(acc[e]) & 0xFFFFFF80u) | gu);
                float m1o = M1[e];
                M1[e] = fmaxf(m1o, ap);
                M2[e] = __builtin_amdgcn_fmed3f(m1o, M2[e], ap);
            }
        }
        __syncthreads();
        b ^= 1;
#pragma unroll
        for (int tl = 0; tl < 4; ++tl) ncc[tl] = ncn[tl];
    }

    // extract idx, cross-lane top-2 merge within each 32-lane half
    int I1[16];
#pragma unroll
    for (int e = 0; e < 16; ++e)
        I1[e] = (int)(((__float_as_uint(M1[e]) & 0x7Fu) << 5) | (unsigned)m);
#pragma unroll
    for (int d = 1; d < 32; d <<= 1) {
#pragma unroll
        for (int e = 0; e < 16; ++e) {
            float oM1 = __shfl_xor(M1[e], d, 64);
            float oM2 = __shfl_xor(M2[e], d, 64);
            int   oI  = __shfl_xor(I1[e], d, 64);
            float lo  = fminf(M1[e], oM1);
            M2[e] = fmaxf(lo, fmaxf(M2[e], oM2));
            bool c = oM1 > M1[e];
            I1[e] = c ? oI : I1[e];
            M1[e] = c ? oM1 : M1[e];
        }
    }
    // C/D row = (reg&3) + 8*(reg>>2) + 4*(lane>>5)
#pragma unroll
    for (int e = 0; e < 16; ++e) {
        int r = (e & 3) + 8 * (e >> 2) + 4 * h;
        if (m == r) {
            int gr = row0 + wv * 32 + r;
            part_a[p * NROWS + gr] = make_float2(M1[e], M2[e]);
            part_i[p * NROWS + gr] = I1[e];
        }
    }
}

// Stage 2: merge parts, flag near-ties into global list, provisional outputs + loss.
__global__ __launch_bounds__(256, 2)
void vq_final(const float* __restrict__ X, const float2* __restrict__ part_a,
              const int* __restrict__ part_i, const float* __restrict__ ET,
              double* __restrict__ accum, int* __restrict__ list_cnt,
              int* __restrict__ list, float* __restrict__ out, int np) {
    __shared__ int   rowidx[128];
    __shared__ float term[128];

    const int t = threadIdx.x;
    const int row0 = blockIdx.x * 128;

    if (t < 128) {
        int gr = row0 + t;
        float M1 = -FLT_MAX, M2 = -FLT_MAX; int bi = 0;
        for (int p = 0; p < np; ++p) {
            float2 pa = part_a[p * NROWS + gr];
            int    pj = part_i[p * NROWS + gr];
            if (pa.x > M1) { M2 = fmaxf(M1, pa.y); M1 = pa.x; bi = pj; }
            else           { M2 = fmaxf(M2, pa.x); }
        }
        rowidx[t] = bi;
        if ((M1 - M2) < 128.0f * TH) {      // near-tie -> exact re-decision kernel
            int pos = atomicAdd(list_cnt, 1);
            list[pos] = gr;
        }
        float M1c = __uint_as_float(__float_as_uint(M1) & 0xFFFFFF80u);
        const float4* xr4 = (const float4*)(X + (size_t)gr * EMBED);
        float sq = 0.f;
#pragma unroll
        for (int q = 0; q < 16; ++q) {
            float4 v = xr4[q];
            sq = fmaf(v.x, v.x, sq); sq = fmaf(v.y, v.y, sq);
            sq = fmaf(v.z, v.z, sq); sq = fmaf(v.w, v.w, sq);
        }
        term[t] = sq - M1c * (1.0f / 128.0f);   // ||x||^2 + score_min
        out[(size_t)NELEM + 1 + gr] = (float)bi;  // provisional idx (as float)
    }
    __syncthreads();

    if (t == 0) {
        float bs = 0.f;
        for (int r = 0; r < 128; ++r) bs += term[r];
        atomicAdd(accum, (double)bs);
    }
    {
        int r = t >> 1, i0 = (t & 1) * 32;
        int j = rowidx[r];
        float* dst = out + (size_t)(row0 + r) * EMBED + i0;
        const float* src = ET + (size_t)j * EMBED + i0;
#pragma unroll
        for (int g = 0; g < 8; ++g)
            *(float4*)(dst + g * 4) = *(const float4*)(src + g * 4);
    }
}

// Stage 3: one block per flagged row — bit-exact fp32 numpy-reference emulation.
// Coalesced E-native float4 loads, 16 independent sequential-FMA chains/thread.
__global__ __launch_bounds__(256)
void vq_fallback(const float* __restrict__ X, const float* __restrict__ E,
                 const float* __restrict__ cbuf, const float* __restrict__ ET,
                 const int* __restrict__ list_cnt, const int* __restrict__ list,
                 float* __restrict__ out) {
    __shared__ float xsh[EMBED];
    __shared__ unsigned long long keysh;
    const int t = threadIdx.x;
    const int cnt = *list_cnt;

    for (int li = blockIdx.x; li < cnt; li += gridDim.x) {
        const int gr = list[li];
        if (t < EMBED) xsh[t] = X[(size_t)gr * EMBED + t];
        if (t == 0) keysh = ~0ull;
        __syncthreads();

        // A: numpy pairwise sum of x*x (n=64: 8 accumulators + tree combine), uniform
        float racc[8];
#pragma unroll
        for (int jq = 0; jq < 8; ++jq) racc[jq] = __fmul_rn(xsh[jq], xsh[jq]);
#pragma unroll
        for (int i = 8; i < 64; i += 8)
#pragma unroll
            for (int jq = 0; jq < 8; ++jq)
                racc[jq] = __fadd_rn(racc[jq], __fmul_rn(xsh[i + jq], xsh[i + jq]));
        float A = __fadd_rn(
            __fadd_rn(__fadd_rn(racc[0], racc[1]), __fadd_rn(racc[2], racc[3])),
            __fadd_rn(__fadd_rn(racc[4], racc[5]), __fadd_rn(racc[6], racc[7])));

        // thread t owns codes j = q*1024 + 4t + r (q,r in 0..3): all loads coalesced
        float mmv[16];
#pragma unroll
        for (int c = 0; c < 16; ++c) mmv[c] = 0.f;
        const float4* E4 = (const float4*)E;
#pragma unroll 8
        for (int i = 0; i < 64; ++i) {
            float xi = xsh[i];
            float4 w0 = E4[(size_t)i * 1024 + 0 * 256 + t];
            float4 w1 = E4[(size_t)i * 1024 + 1 * 256 + t];
            float4 w2 = E4[(size_t)i * 1024 + 2 * 256 + t];
            float4 w3 = E4[(size_t)i * 1024 + 3 * 256 + t];
            mmv[ 0] = fmaf(xi, w0.x, mmv[ 0]); mmv[ 1] = fmaf(xi, w0.y, mmv[ 1]);
            mmv[ 2] = fmaf(xi, w0.z, mmv[ 2]); mmv[ 3] = fmaf(xi, w0.w, mmv[ 3]);
            mmv[ 4] = fmaf(xi, w1.x, mmv[ 4]); mmv[ 5] = fmaf(xi, w1.y, mmv[ 5]);
            mmv[ 6] = fmaf(xi, w1.z, mmv[ 6]); mmv[ 7] = fmaf(xi, w1.w, mmv[ 7]);
            mmv[ 8] = fmaf(xi, w2.x, mmv[ 8]); mmv[ 9] = fmaf(xi, w2.y, mmv[ 9]);
            mmv[10] = fmaf(xi, w2.z, mmv[10]); mmv[11] = fmaf(xi, w2.w, mmv[11]);
            mmv[12] = fmaf(xi, w3.x, mmv[12]); mmv[13] = fmaf(xi, w3.y, mmv[13]);
            mmv[14] = fmaf(xi, w3.z, mmv[14]); mmv[15] = fmaf(xi, w3.w, mmv[15]);
        }
        unsigned long long bestk = ~0ull;
        const float4* C4 = (const float4*)cbuf;
#pragma unroll
        for (int q = 0; q < 4; ++q) {
            float4 cv = C4[q * 256 + t];
            float cc[4] = {cv.x, cv.y, cv.z, cv.w};
#pragma unroll
            for (int r = 0; r < 4; ++r) {
                int j = q * 1024 + 4 * t + r;
                float d = __fadd_rn(__fsub_rn(A, __fmul_rn(2.f, mmv[q * 4 + r])), cc[r]);
                unsigned ud = __float_as_uint(d);
                ud = (ud & 0x80000000u) ? ~ud : (ud | 0x80000000u);  // monotone float->uint
                unsigned long long key = ((unsigned long long)ud << 32) | (unsigned)j;
                bestk = key < bestk ? key : bestk;
            }
        }
        atomicMin(&keysh, bestk);
        __syncthreads();
        int bj = (int)(keysh & 0xFFFFFFFFu);
        if (t == 0) out[(size_t)NELEM + 1 + gr] = (float)bj;   // corrected idx
        if (t < 16)                                            // corrected quantized row
            *(float4*)(out + (size_t)gr * EMBED + t * 4) =
                *(const float4*)(ET + (size_t)bj * EMBED + t * 4);
        __syncthreads();
    }
}

// Self-contained safety net if ws is too small: bf16 3-split, on-the-fly convert.
__global__ __launch_bounds__(256)
void vq_small(const float* __restrict__ X, const float* __restrict__ E,
              const float* __restrict__ cbuf, double* __restrict__ accum,
              float* __restrict__ out) {
    __shared__ float rowm1[128], rowsq[128];
    __shared__ int   rowidx[128], rowflg[128];
    __shared__ float xsh[EMBED];
    __shared__ unsigned long long keysh[128];

    const int t  = threadIdx.x;
    const int l  = t & 63, wv = t >> 6;
    const int m  = l & 31, h  = l >> 5;
    const int row0 = blockIdx.x * 128;

    bf16x8 ah[4], al[4];
    float sqreg;
    {
        const float* xrow = X + (size_t)(row0 + wv * 32 + m) * EMBED;
        float sq = 0.f;
#pragma unroll
        for (int kk = 0; kk < 4; ++kk) {
            int kb = kk * 16 + h * 8;
            float4 v0 = *(const float4*)(xrow + kb);
            float4 v1 = *(const float4*)(xrow + kb + 4);
            float xv[8] = {v0.x, v0.y, v0.z, v0.w, v1.x, v1.y, v1.z, v1.w};
#pragma unroll
            for (int j = 0; j < 8; ++j) {
                sq = fmaf(xv[j], xv[j], sq);
                unsigned short hi = f2bf(xv[j]);
                ah[kk][j] = (short)hi;
                al[kk][j] = (short)f2bf(xv[j] - bf2f(hi));
            }
        }
        sq += __shfl_xor(sq, 32, 64);
        sqreg = sq;
    }

    float M1[16], M2[16];
#pragma unroll
    for (int e = 0; e < 16; ++e) { M1[e] = -FLT_MAX; M2[e] = -FLT_MAX; }

#pragma unroll 1
    for (int g = 0; g < 128; ++g) {
        bf16x8 B[8];
        int n = g * 32 + m;
#pragma unroll
        for (int kk = 0; kk < 4; ++kk) {
            const float* ec = E + (size_t)(kk * 16 + h * 8) * CODES + n;
            bf16x8 vh, vl;
#pragma unroll
            for (int j = 0; j < 8; ++j) {
                float e = ec[(size_t)j * CODES];
                unsigned short hi = f2bf(e);
                vh[j] = (short)hi;
                vl[j] = (short)f2bf(e - bf2f(hi));
            }
            B[kk * 2] = vh; B[kk * 2 + 1] = vl;
        }
        float nc = -0.5f * cbuf[g * 32 + m];
        f32x16 acc;
#pragma unroll
        for (int e = 0; e < 16; ++e) acc[e] = nc;
#pragma unroll
        for (int kk = 0; kk < 4; ++kk) {
            acc = __builtin_amdgcn_mfma_f32_32x32x16_bf16(ah[kk], B[kk * 2],     acc, 0, 0, 0);
            acc = __builtin_amdgcn_mfma_f32_32x32x16_bf16(ah[kk], B[kk * 2 + 1], acc, 0, 0, 0);
            acc = __builtin_amdgcn_mfma_f32_32x32x16_bf16(al[kk], B[kk * 2],     acc, 0, 0, 0);
        }
        unsigned gu = (unsigned)g;
#pragma unroll
        for (int e = 0; e < 16; ++e) {
            float ap = __uint_as_float((__float_as_uint(acc[e]) & 0xFFFFFF80u) | gu);
            float m1o = M1[e];
            M1[e] = fmaxf(m1o, ap);
            M2[e] = __builtin_amdgcn_fmed3f(m1o, M2[e], ap);
        }
    }

    int I1[16];
#pragma unroll
    for (int e = 0; e < 16; ++e)
        I1[e] = (int)(((__float_as_uint(M1[e]) & 0x7Fu) << 5) | (unsigned)m);
#pragma unroll
    for (int d = 1; d < 32; d <<= 1) {
#pragma unroll
        for (int e = 0; e < 16; ++e) {
            float oM1 = __shfl_xor(M1[e], d, 64);
            float oM2 = __shfl_xor(M2[e], d, 64);
            int   oI  = __shfl_xor(I1[e], d, 64);
            float lo  = fminf(M1[e], oM1);
            M2[e] = fmaxf(lo, fmaxf(M2[e], oM2));
            bool c = oM1 > M1[e];
            I1[e] = c ? oI : I1[e];
            M1[e] = c ? oM1 : M1[e];
        }
    }
    if (h == 0) rowsq[wv * 32 + m] = sqreg;
#pragma unroll
    for (int e = 0; e < 16; ++e) {
        int r = (e & 3) + 8 * (e >> 2) + 4 * h;
        if (m == r) {
            rowm1[wv * 32 + r]  = __uint_as_float(__float_as_uint(M1[e]) & 0xFFFFFF80u);
            rowidx[wv * 32 + r] = I1[e];
            rowflg[wv * 32 + r] = (2.f * (M1[e] - M2[e]) < 2e-4f) ? 1 : 0;
        }
    }
    if (t < 128) keysh[t] = ~0ull;
    __syncthreads();

#pragma unroll 1
    for (int r = 0; r < 128; ++r) {
        if (rowflg[r] == 0) continue;
        if (t < EMBED) xsh[t] = X[(size_t)(row0 + r) * EMBED + t];
        __syncthreads();
        float racc[8];
#pragma unroll
        for (int jq = 0; jq < 8; ++jq) racc[jq] = __fmul_rn(xsh[jq], xsh[jq]);
#pragma unroll
        for (int i = 8; i < 64; i += 8)
#pragma unroll
            for (int jq = 0; jq < 8; ++jq)
                racc[jq] = __fadd_rn(racc[jq], __fmul_rn(xsh[i + jq], xsh[i + jq]));
        float A = __fadd_rn(
            __fadd_rn(__fadd_rn(racc[0], racc[1]), __fadd_rn(racc[2], racc[3])),
            __fadd_rn(__fadd_rn(racc[4], racc[5]), __fadd_rn(racc[6], racc[7])));
        float mmv[16];
#pragma unroll
        for (int jj = 0; jj < 16; ++jj) mmv[jj] = 0.f;
#pragma unroll 4
        for (int i = 0; i < 64; ++i) {
            float xi = xsh[i];
            const float* er = E + (size_t)i * CODES + t;
#pragma unroll
            for (int jj = 0; jj < 16; ++jj)
                mmv[jj] = fmaf(xi, er[jj * 256], mmv[jj]);
        }
        unsigned long long bestk = ~0ull;
#pragma unroll
        for (int jj = 0; jj < 16; ++jj) {
            int j = jj * 256 + t;
            float d = __fadd_rn(__fsub_rn(A, __fmul_rn(2.f, mmv[jj])), cbuf[j]);
            unsigned ud = __float_as_uint(d);
            ud = (ud & 0x80000000u) ? ~ud : (ud | 0x80000000u);
            unsigned long long key = ((unsigned long long)ud << 32) | (unsigned)j;
            bestk = key < bestk ? key : bestk;
        }
        atomicMin(&keysh[r], bestk);
        __syncthreads();
    }
    if (t < 128 && rowflg[t]) rowidx[t] = (int)(keysh[t] & 0xFFFFFFFFu);
    __syncthreads();

    if (t < 128) out[(size_t)NELEM + 1 + row0 + t] = (float)rowidx[t];
    if (t == 0) {
        float bs = 0.f;
        for (int r = 0; r < 128; ++r) bs += rowsq[r] - 2.f * rowm1[r];
        atomicAdd(accum, (double)bs);
    }
    {
        int r = t >> 1, i0 = (t & 1) * 32;
        int j = rowidx[r];
        float* dst = out + (size_t)(row0 + r) * EMBED + i0;
#pragma unroll
        for (int g = 0; g < 8; ++g) {
            float4 v;
            v.x = E[(size_t)(i0 + g * 4 + 0) * CODES + j];
            v.y = E[(size_t)(i0 + g * 4 + 1) * CODES + j];
            v.z = E[(size_t)(i0 + g * 4 + 2) * CODES + j];
            v.w = E[(size_t)(i0 + g * 4 + 3) * CODES + j];
            *(float4*)(dst + g * 4) = v;
        }
    }
}

__global__ void vq_finalize(const double* __restrict__ accum, float* __restrict__ out) {
    out[NELEM] = (float)(0.25 * (*accum) / (double)NELEM);
}

extern "C" void kernel_launch(void* const* d_in, const int* in_sizes, int n_in,
                              void* d_out, int out_size, void* d_ws, size_t ws_size,
                              hipStream_t stream) {
    const float* X = (const float*)d_in[0];   // (512, 8192, 1) f32 -> 65536 rows x 64
    const float* E = (const float*)d_in[1];   // (64, 4096) f32 row-major
    float* out = (float*)d_out;
    float*  cbuf     = (float*)d_ws;
    double* accum    = (double*)((char*)d_ws + WS_ACCUM);
    int*    list_cnt = (int*)((char*)d_ws + WS_LISTCNT);
    f16x8*  packed   = (f16x8*)((char*)d_ws + WS_PACKED);
    float*  ET       = (float*)((char*)d_ws + WS_ET);
    int*    list     = (int*)((char*)d_ws + WS_LIST);
    float2* part_a   = (float2*)((char*)d_ws + WS_PART);

    // npl=2 (quarters) needs ~4.78 MB; npl=1 (halves) ~3.28 MB; else small path
    int npl = 0;
    if (ws_size >= (size_t)WS_PART + 4u * NROWS * 12u)      npl = 2;
    else if (ws_size >= (size_t)WS_PART + 2u * NROWS * 12u) npl = 1;
    const bool big = (npl > 0);
    const int  np  = 1 << npl;
    int* part_i = (int*)((char*)d_ws + WS_PART + (size_t)np * NROWS * 8u);

    vq_setup<<<big ? 400 : 16, 256, 0, stream>>>(E, cbuf, accum, list_cnt, packed, ET,
                                                 big ? 1 : 0);
    if (big) {
        vq_partial<<<512 << npl, 256, 0, stream>>>(X, cbuf, packed, part_a, part_i, npl);
        vq_final<<<512, 256, 0, stream>>>(X, part_a, part_i, ET, accum, list_cnt, list,
                                          out, np);
        vq_fallback<<<512, 256, 0, stream>>>(X, E, cbuf, ET, list_cnt, list, out);
    } else {
        vq_small<<<512, 256, 0, stream>>>(X, E, cbuf, accum, out);
    }
    vq_finalize<<<1, 1, 0, stream>>>(accum, out);
}